// Round 1
// baseline (644.252 us; speedup 1.0000x reference)
//
#include <hip/hip_runtime.h>
#include <hip/hip_bf16.h>
#include <stdint.h>

typedef __bf16 bf16_t;
typedef __bf16 bf16x8 __attribute__((ext_vector_type(8)));
typedef __bf16 bf16x4 __attribute__((ext_vector_type(4)));
typedef float  f32x4  __attribute__((ext_vector_type(4)));

// async global->LDS, 16B per lane
#define GL_LDS16(g, l)                                                         \
  __builtin_amdgcn_global_load_lds(                                            \
      (const __attribute__((address_space(1))) void*)(g),                      \
      (__attribute__((address_space(3))) void*)(l), 16, 0, 0)

// ---------------------------------------------------------------------------
// fp32 -> bf16 weight conversion: grid covers exactly 1M elements (1024 blocks)
// ---------------------------------------------------------------------------
__global__ void cvt_w_kernel(const float* __restrict__ src, bf16_t* __restrict__ dst) {
  const int i = (blockIdx.x * 256 + threadIdx.x) * 4;
  f32x4 v = *(const f32x4*)(src + i);
  bf16x4 b;
  b[0] = (bf16_t)v[0]; b[1] = (bf16_t)v[1]; b[2] = (bf16_t)v[2]; b[3] = (bf16_t)v[3];
  *(bf16x4*)(dst + i) = b;
}

// ---------------------------------------------------------------------------
// GEMM: C[M=8192,N=1024] = A[M,1024] @ W[N,1024]^T   (W row-major [out,in])
// AMODE 0: A fp32 (reg-staged + converted)   AMODE 1: A bf16 (global_load_lds)
// OMODE 0: bf16 out, permuted to [n][h][s][d]  OMODE 1: fp32 out, row-major
// 128x128 tile, BK=64, 4 waves (2x2), mfma 16x16x32 bf16. Linear LDS (no
// swizzle: T2 is null at 128^2 + 2-phase per m228d, and one-sided swizzle
// with global_load_lds is a correctness trap).
// ---------------------------------------------------------------------------
template <int AMODE, int OMODE>
__global__ __launch_bounds__(256) void gemm_kernel(const void* __restrict__ Aptr,
                                                   const bf16_t* __restrict__ Wptr,
                                                   void* __restrict__ Optr) {
  __shared__ char ldsA[128 * 64 * 2];
  __shared__ char ldsB[128 * 64 * 2];
  const int t  = threadIdx.x;
  const int l  = t & 63;
  const int wv = t >> 6;
  const int wr = wv >> 1, wc = wv & 1;
  const int lq = l & 15, lg = l >> 4;
  const int m0 = blockIdx.x * 128;
  const int n0 = blockIdx.y * 128;

  f32x4 acc[4][4] = {};

  for (int k0 = 0; k0 < 1024; k0 += 64) {
    // ---- stage W tile [128][64] bf16 via async direct-to-LDS
#pragma unroll
    for (int it = 0; it < 4; ++it) {
      const int dst = it * 4096 + t * 16;
      const int row = dst >> 7;            // 128B per row
      const int col = (dst & 127) >> 1;    // bf16 col
      GL_LDS16(Wptr + (size_t)(n0 + row) * 1024 + k0 + col, ldsB + dst);
    }
    // ---- stage A tile
    if constexpr (AMODE == 0) {
      const float* Af = (const float*)Aptr;
      const int row   = t >> 1;
      const int cbase = (t & 1) * 32;
#pragma unroll
      for (int u = 0; u < 8; ++u) {
        const int colf = cbase + u * 4;
        f32x4 v = *(const f32x4*)(Af + (size_t)(m0 + row) * 1024 + k0 + colf);
        bf16x4 b;
        b[0] = (bf16_t)v[0]; b[1] = (bf16_t)v[1]; b[2] = (bf16_t)v[2]; b[3] = (bf16_t)v[3];
        *(bf16x4*)(ldsA + row * 128 + colf * 2) = b;
      }
    } else {
      const bf16_t* Ab = (const bf16_t*)Aptr;
#pragma unroll
      for (int it = 0; it < 4; ++it) {
        const int dst = it * 4096 + t * 16;
        const int row = dst >> 7;
        const int col = (dst & 127) >> 1;
        GL_LDS16(Ab + (size_t)(m0 + row) * 1024 + k0 + col, ldsA + dst);
      }
    }
    __syncthreads();

    // ---- compute: 2 k-chunks of 32, 16 MFMAs each
#pragma unroll
    for (int kc = 0; kc < 2; ++kc) {
      bf16x8 af[4], bfr[4];
#pragma unroll
      for (int mm = 0; mm < 4; ++mm)
        af[mm] = *(const bf16x8*)(ldsA + (wr * 64 + mm * 16 + lq) * 128 + kc * 64 + lg * 16);
#pragma unroll
      for (int nn = 0; nn < 4; ++nn)
        bfr[nn] = *(const bf16x8*)(ldsB + (wc * 64 + nn * 16 + lq) * 128 + kc * 64 + lg * 16);
#pragma unroll
      for (int mm = 0; mm < 4; ++mm)
#pragma unroll
        for (int nn = 0; nn < 4; ++nn)
          acc[mm][nn] =
              __builtin_amdgcn_mfma_f32_16x16x32_bf16(af[mm], bfr[nn], acc[mm][nn], 0, 0, 0);
    }
    __syncthreads();
  }

  // ---- epilogue.  D frag layout: row = 4*lg + i, col = lq  (m89-verified)
  if constexpr (OMODE == 1) {
    float* O = (float*)Optr;
#pragma unroll
    for (int mm = 0; mm < 4; ++mm)
#pragma unroll
      for (int nn = 0; nn < 4; ++nn) {
        const int r = m0 + wr * 64 + mm * 16 + lg * 4;
        const int c = n0 + wc * 64 + nn * 16 + lq;
#pragma unroll
        for (int i = 0; i < 4; ++i) O[(size_t)(r + i) * 1024 + c] = acc[mm][nn][i];
      }
  } else {
    bf16_t* O = (bf16_t*)Optr;  // [n][h][s][d]
#pragma unroll
    for (int mm = 0; mm < 4; ++mm)
#pragma unroll
      for (int nn = 0; nn < 4; ++nn) {
#pragma unroll
        for (int i = 0; i < 4; ++i) {
          const int r  = m0 + wr * 64 + mm * 16 + lg * 4 + i;
          const int c  = n0 + wc * 64 + nn * 16 + lq;
          const int nb = r >> 11, s = r & 2047;
          const int hh = c >> 6, d = c & 63;
          O[(((size_t)nb * 16 + hh) * 2048 + s) * 64 + d] = (bf16_t)acc[mm][nn][i];
        }
      }
  }
}

// ---------------------------------------------------------------------------
// Flash attention. q,k,v bf16 [n][h][s][64]; out bf16 [n][s][h][64].
// 4 independent waves per block, wave owns 16 q rows; no LDS at all (K/V per
// head = 512KB, L2-resident; 4 waves share via L1/L2).
// Swapped QK^T: S^T = mfma(K_frag, Q_frag). K rows are loaded with a permuted
// row->lane map (perm(m) = 8*(m>>2) + (m&3) [+4 for tile1]) so that after the
// two 16-key score tiles, lane group g holds keys 8g..8g+7 == exactly the
// B-operand k-slots of the PV 16x16x32 MFMA. Zero cross-lane data movement
// between softmax and PV.
// ---------------------------------------------------------------------------
__global__ __launch_bounds__(256) void attn_kernel(const bf16_t* __restrict__ Q,
                                                   const bf16_t* __restrict__ K,
                                                   const bf16_t* __restrict__ V,
                                                   bf16_t* __restrict__ AO) {
  const int t  = threadIdx.x;
  const int l  = t & 63;
  const int wv = t >> 6;
  const int lq = l & 15, lg = l >> 4;
  const int h = blockIdx.y, n = blockIdx.z;
  const int s0 = blockIdx.x * 64 + wv * 16;
  const size_t hoff = ((size_t)(n * 16 + h)) * 2048 * 64;
  const bf16_t* Qb = Q + hoff;
  const bf16_t* Kb = K + hoff;
  const bf16_t* Vb = V + hoff;

  // Q as B-operand: lane holds Q[s0+lq][c*32 + 8*lg + j]
  const bf16x8 qf0 = *(const bf16x8*)(Qb + (s0 + lq) * 64 + lg * 8);
  const bf16x8 qf1 = *(const bf16x8*)(Qb + (s0 + lq) * 64 + 32 + lg * 8);

  f32x4 o0 = {}, o1 = {}, o2 = {}, o3 = {};
  float mrun = -1e30f, lsum = 0.f;
  const int krperm  = 8 * (lq >> 2) + (lq & 3);
  const float SCALE = 0.03125f;  // 1/sqrt(1024)

  for (int kv = 0; kv < 2048; kv += 32) {
    const bf16_t* Kr = Kb + (size_t)(kv + krperm) * 64 + lg * 8;
    bf16x8 kf00 = *(const bf16x8*)(Kr);
    bf16x8 kf01 = *(const bf16x8*)(Kr + 32);
    bf16x8 kf10 = *(const bf16x8*)(Kr + 256);        // +4 rows
    bf16x8 kf11 = *(const bf16x8*)(Kr + 256 + 32);
    f32x4 z = {};
    f32x4 st0 = __builtin_amdgcn_mfma_f32_16x16x32_bf16(kf00, qf0, z, 0, 0, 0);
    st0 = __builtin_amdgcn_mfma_f32_16x16x32_bf16(kf01, qf1, st0, 0, 0, 0);
    f32x4 st1 = __builtin_amdgcn_mfma_f32_16x16x32_bf16(kf10, qf0, z, 0, 0, 0);
    st1 = __builtin_amdgcn_mfma_f32_16x16x32_bf16(kf11, qf1, st1, 0, 0, 0);
    // lane now holds scores for keys kv + 8*lg + {0..3} (st0) and {4..7} (st1),
    // for q column s0+lq.

    // V as A-operand of PV: lane holds V[kv + 8*lg + j][c*16 + lq]
    const bf16_t* Vr = Vb + (size_t)(kv + lg * 8) * 64 + lq;
    bf16x8 vf0, vf1, vf2, vf3;
#pragma unroll
    for (int j = 0; j < 8; ++j) {
      vf0[j] = Vr[j * 64];
      vf1[j] = Vr[j * 64 + 16];
      vf2[j] = Vr[j * 64 + 32];
      vf3[j] = Vr[j * 64 + 48];
    }

    float s[8];
#pragma unroll
    for (int i = 0; i < 4; ++i) { s[i] = st0[i] * SCALE; s[4 + i] = st1[i] * SCALE; }
    float tm = s[0];
#pragma unroll
    for (int j = 1; j < 8; ++j) tm = fmaxf(tm, s[j]);
    tm = fmaxf(tm, __shfl_xor(tm, 16));
    tm = fmaxf(tm, __shfl_xor(tm, 32));
    const float mnew = fmaxf(mrun, tm);
    const float corr = __expf(mrun - mnew);
    float p[8], ps = 0.f;
#pragma unroll
    for (int j = 0; j < 8; ++j) { p[j] = __expf(s[j] - mnew); ps += p[j]; }
    ps += __shfl_xor(ps, 16);
    ps += __shfl_xor(ps, 32);
    lsum = lsum * corr + ps;
    mrun = mnew;

    bf16x8 pf;
#pragma unroll
    for (int j = 0; j < 8; ++j) pf[j] = (bf16_t)p[j];
#pragma unroll
    for (int i = 0; i < 4; ++i) { o0[i] *= corr; o1[i] *= corr; o2[i] *= corr; o3[i] *= corr; }
    o0 = __builtin_amdgcn_mfma_f32_16x16x32_bf16(vf0, pf, o0, 0, 0, 0);
    o1 = __builtin_amdgcn_mfma_f32_16x16x32_bf16(vf1, pf, o1, 0, 0, 0);
    o2 = __builtin_amdgcn_mfma_f32_16x16x32_bf16(vf2, pf, o2, 0, 0, 0);
    o3 = __builtin_amdgcn_mfma_f32_16x16x32_bf16(vf3, pf, o3, 0, 0, 0);
  }

  // o[c] lane layout: O[s0+lq][c*16 + 4*lg + i]
  const float inv = 1.f / lsum;
  bf16_t* AOb = AO + (((size_t)(n * 2048 + s0 + lq)) * 16 + h) * 64 + lg * 4;
  bf16x4 w;
#pragma unroll
  for (int i = 0; i < 4; ++i) w[i] = (bf16_t)(o0[i] * inv);
  *(bf16x4*)(AOb + 0) = w;
#pragma unroll
  for (int i = 0; i < 4; ++i) w[i] = (bf16_t)(o1[i] * inv);
  *(bf16x4*)(AOb + 16) = w;
#pragma unroll
  for (int i = 0; i < 4; ++i) w[i] = (bf16_t)(o2[i] * inv);
  *(bf16x4*)(AOb + 32) = w;
#pragma unroll
  for (int i = 0; i < 4; ++i) w[i] = (bf16_t)(o3[i] * inv);
  *(bf16x4*)(AOb + 48) = w;
}

// ---------------------------------------------------------------------------
extern "C" void kernel_launch(void* const* d_in, const int* in_sizes, int n_in,
                              void* d_out, int out_size, void* d_ws, size_t ws_size,
                              hipStream_t stream) {
  const float* values = (const float*)d_in[0];
  const float* keys   = (const float*)d_in[1];
  const float* query  = (const float*)d_in[2];
  const float* Wv     = (const float*)d_in[3];
  const float* Wk     = (const float*)d_in[4];
  const float* Wq     = (const float*)d_in[5];
  const float* Wo     = (const float*)d_in[6];
  float* out          = (float*)d_out;

  // workspace layout (72 MB):
  // 4 x 2MB bf16 weights, then 4 x 16MB bf16 tensors (q, k, v, attn_out)
  char* ws     = (char*)d_ws;
  bf16_t* wv_b = (bf16_t*)ws;
  bf16_t* wk_b = wv_b + (1u << 20);
  bf16_t* wq_b = wk_b + (1u << 20);
  bf16_t* wo_b = wq_b + (1u << 20);
  bf16_t* q_b  = wo_b + (1u << 20);
  bf16_t* k_b  = q_b + (8u << 20);
  bf16_t* v_b  = k_b + (8u << 20);
  bf16_t* ao_b = v_b + (8u << 20);

  cvt_w_kernel<<<1024, 256, 0, stream>>>(Wv, wv_b);
  cvt_w_kernel<<<1024, 256, 0, stream>>>(Wk, wk_b);
  cvt_w_kernel<<<1024, 256, 0, stream>>>(Wq, wq_b);
  cvt_w_kernel<<<1024, 256, 0, stream>>>(Wo, wo_b);

  dim3 gg(64, 8);
  gemm_kernel<0, 0><<<gg, 256, 0, stream>>>(query, wq_b, q_b);
  gemm_kernel<0, 0><<<gg, 256, 0, stream>>>(keys, wk_b, k_b);
  gemm_kernel<0, 0><<<gg, 256, 0, stream>>>(values, wv_b, v_b);

  attn_kernel<<<dim3(32, 16, 4), 256, 0, stream>>>(q_b, k_b, v_b, ao_b);

  gemm_kernel<1, 1><<<gg, 256, 0, stream>>>(ao_b, wo_b, out);
}

// Round 2
// 527.202 us; speedup vs baseline: 1.2220x; 1.2220x over previous
//
#include <hip/hip_runtime.h>
#include <hip/hip_bf16.h>
#include <stdint.h>

typedef __bf16 bf16_t;
typedef __bf16 bf16x8 __attribute__((ext_vector_type(8)));
typedef __bf16 bf16x4 __attribute__((ext_vector_type(4)));
typedef float  f32x4  __attribute__((ext_vector_type(4)));

// async global->LDS, 16B per lane
#define GL_LDS16(g, l)                                                         \
  __builtin_amdgcn_global_load_lds(                                            \
      (const __attribute__((address_space(1))) void*)(g),                      \
      (__attribute__((address_space(3))) void*)(l), 16, 0, 0)

// ---------------------------------------------------------------------------
// fp32 -> bf16 conversion of the 4 weight matrices (contiguous 4 x 1M bf16 dst)
// grid = 4096 blocks x 256 threads, 4 elems/thread
// ---------------------------------------------------------------------------
__global__ void cvt_w_kernel(const float* __restrict__ s0, const float* __restrict__ s1,
                             const float* __restrict__ s2, const float* __restrict__ s3,
                             bf16_t* __restrict__ dst) {
  const int b = blockIdx.x;
  const float* src = (b < 1024) ? s0 : (b < 2048) ? s1 : (b < 3072) ? s2 : s3;
  const int i = ((b & 1023) * 256 + threadIdx.x) * 4;
  f32x4 v = *(const f32x4*)(src + i);
  bf16x4 w;
  w[0] = (bf16_t)v[0]; w[1] = (bf16_t)v[1]; w[2] = (bf16_t)v[2]; w[3] = (bf16_t)v[3];
  *(bf16x4*)(dst + (size_t)(b >> 10) * (1u << 20) + i) = w;
}

// ---------------------------------------------------------------------------
// GEMM: C[M=8192,N=1024] = A[M,1024] @ W[N,1024]^T   (W row-major [out,in])
// AMODE 0: A fp32 (reg-staged + converted)   AMODE 1: A bf16 (global_load_lds)
// OMODE 0: bf16 out, permuted [n][h][s][d]
// OMODE 1: fp32 out, row-major
// OMODE 2: bf16 out, transposed [n][h][d][s]   (for V -> Vt)
// 128x128 tile, BK=64, 4 waves (2x2), mfma 16x16x32 bf16, linear LDS.
// ---------------------------------------------------------------------------
template <int AMODE, int OMODE>
__global__ __launch_bounds__(256) void gemm_kernel(const void* __restrict__ Aptr,
                                                   const bf16_t* __restrict__ Wptr,
                                                   void* __restrict__ Optr) {
  __shared__ char ldsA[128 * 64 * 2];
  __shared__ char ldsB[128 * 64 * 2];
  const int t  = threadIdx.x;
  const int l  = t & 63;
  const int wv = t >> 6;
  const int wr = wv >> 1, wc = wv & 1;
  const int lq = l & 15, lg = l >> 4;
  const int m0 = blockIdx.x * 128;
  const int n0 = blockIdx.y * 128;

  f32x4 acc[4][4] = {};

  for (int k0 = 0; k0 < 1024; k0 += 64) {
#pragma unroll
    for (int it = 0; it < 4; ++it) {
      const int dst = it * 4096 + t * 16;
      const int row = dst >> 7;
      const int col = (dst & 127) >> 1;
      GL_LDS16(Wptr + (size_t)(n0 + row) * 1024 + k0 + col, ldsB + dst);
    }
    if constexpr (AMODE == 0) {
      const float* Af = (const float*)Aptr;
      const int row   = t >> 1;
      const int cbase = (t & 1) * 32;
#pragma unroll
      for (int u = 0; u < 8; ++u) {
        const int colf = cbase + u * 4;
        f32x4 v = *(const f32x4*)(Af + (size_t)(m0 + row) * 1024 + k0 + colf);
        bf16x4 b;
        b[0] = (bf16_t)v[0]; b[1] = (bf16_t)v[1]; b[2] = (bf16_t)v[2]; b[3] = (bf16_t)v[3];
        *(bf16x4*)(ldsA + row * 128 + colf * 2) = b;
      }
    } else {
      const bf16_t* Ab = (const bf16_t*)Aptr;
#pragma unroll
      for (int it = 0; it < 4; ++it) {
        const int dst = it * 4096 + t * 16;
        const int row = dst >> 7;
        const int col = (dst & 127) >> 1;
        GL_LDS16(Ab + (size_t)(m0 + row) * 1024 + k0 + col, ldsA + dst);
      }
    }
    __syncthreads();

#pragma unroll
    for (int kc = 0; kc < 2; ++kc) {
      bf16x8 af[4], bfr[4];
#pragma unroll
      for (int mm = 0; mm < 4; ++mm)
        af[mm] = *(const bf16x8*)(ldsA + (wr * 64 + mm * 16 + lq) * 128 + kc * 64 + lg * 16);
#pragma unroll
      for (int nn = 0; nn < 4; ++nn)
        bfr[nn] = *(const bf16x8*)(ldsB + (wc * 64 + nn * 16 + lq) * 128 + kc * 64 + lg * 16);
#pragma unroll
      for (int mm = 0; mm < 4; ++mm)
#pragma unroll
        for (int nn = 0; nn < 4; ++nn)
          acc[mm][nn] =
              __builtin_amdgcn_mfma_f32_16x16x32_bf16(af[mm], bfr[nn], acc[mm][nn], 0, 0, 0);
    }
    __syncthreads();
  }

  // D frag layout: row = 4*lg + i, col = lq  (m89-verified)
  if constexpr (OMODE == 1) {
    float* O = (float*)Optr;
#pragma unroll
    for (int mm = 0; mm < 4; ++mm)
#pragma unroll
      for (int nn = 0; nn < 4; ++nn) {
        const int r = m0 + wr * 64 + mm * 16 + lg * 4;
        const int c = n0 + wc * 64 + nn * 16 + lq;
#pragma unroll
        for (int i = 0; i < 4; ++i) O[(size_t)(r + i) * 1024 + c] = acc[mm][nn][i];
      }
  } else if constexpr (OMODE == 0) {
    bf16_t* O = (bf16_t*)Optr;  // [n][h][s][d]
#pragma unroll
    for (int mm = 0; mm < 4; ++mm)
#pragma unroll
      for (int nn = 0; nn < 4; ++nn) {
#pragma unroll
        for (int i = 0; i < 4; ++i) {
          const int r  = m0 + wr * 64 + mm * 16 + lg * 4 + i;
          const int c  = n0 + wc * 64 + nn * 16 + lq;
          const int nb = r >> 11, s = r & 2047;
          const int hh = c >> 6, d = c & 63;
          O[(((size_t)nb * 16 + hh) * 2048 + s) * 64 + d] = (bf16_t)acc[mm][nn][i];
        }
      }
  } else {
    bf16_t* O = (bf16_t*)Optr;  // Vt [n][h][d][s]; 4 consecutive s per lane -> bf16x4 store
#pragma unroll
    for (int mm = 0; mm < 4; ++mm)
#pragma unroll
      for (int nn = 0; nn < 4; ++nn) {
        const int r  = m0 + wr * 64 + mm * 16 + lg * 4;  // s-dim, multiple of 4
        const int c  = n0 + wc * 64 + nn * 16 + lq;      // h*64+d
        const int nb = r >> 11, s = r & 2047;
        const int hh = c >> 6, d = c & 63;
        bf16x4 w;
#pragma unroll
        for (int i = 0; i < 4; ++i) w[i] = (bf16_t)acc[mm][nn][i];
        *(bf16x4*)(O + (((size_t)nb * 16 + hh) * 64 + d) * 2048 + s) = w;
      }
  }
}

// ---------------------------------------------------------------------------
// Flash attention. q,k bf16 [n][h][s][64]; v bf16 TRANSPOSED [n][h][d][s];
// out bf16 [n][s][h][64].
// 4 independent waves/block; each wave owns 32 q rows (two 16-row tiles
// sharing the K and V fragments). No LDS: K/V per head = 512KB, L2-resident;
// the 4 waves read identical addresses in lockstep -> L1 broadcast.
// Swapped QK^T (S^T = mfma(K,Q)) with permuted key->lane map so the score
// registers feed PV's B-operand with zero cross-lane movement. V^T fragments
// (A-operand of O^T = V^T P^T) are contiguous bf16x8 loads from Vt.
// ---------------------------------------------------------------------------
__device__ __forceinline__ void sm_pv(const f32x4& s0v, const f32x4& s1v, float& mrun,
                                      float& lsum, const bf16x8 vf[4], f32x4 o[4]) {
  const float SCALE = 0.03125f;  // 1/sqrt(1024)
  float s[8];
#pragma unroll
  for (int i = 0; i < 4; ++i) { s[i] = s0v[i] * SCALE; s[4 + i] = s1v[i] * SCALE; }
  float tm = s[0];
#pragma unroll
  for (int j = 1; j < 8; ++j) tm = fmaxf(tm, s[j]);
  tm = fmaxf(tm, __shfl_xor(tm, 16));
  tm = fmaxf(tm, __shfl_xor(tm, 32));
  const float mnew = fmaxf(mrun, tm);
  const float corr = __expf(mrun - mnew);
  float p[8], ps = 0.f;
#pragma unroll
  for (int j = 0; j < 8; ++j) { p[j] = __expf(s[j] - mnew); ps += p[j]; }
  ps += __shfl_xor(ps, 16);
  ps += __shfl_xor(ps, 32);
  lsum = lsum * corr + ps;
  mrun = mnew;
  bf16x8 pf;
#pragma unroll
  for (int j = 0; j < 8; ++j) pf[j] = (bf16_t)p[j];
#pragma unroll
  for (int c = 0; c < 4; ++c) {
#pragma unroll
    for (int i = 0; i < 4; ++i) o[c][i] *= corr;
    o[c] = __builtin_amdgcn_mfma_f32_16x16x32_bf16(vf[c], pf, o[c], 0, 0, 0);
  }
}

__global__ __launch_bounds__(256) void attn_kernel(const bf16_t* __restrict__ Q,
                                                   const bf16_t* __restrict__ K,
                                                   const bf16_t* __restrict__ Vt,
                                                   bf16_t* __restrict__ AO) {
  const int t  = threadIdx.x;
  const int l  = t & 63;
  const int wv = t >> 6;
  const int lq = l & 15, lg = l >> 4;
  const int h = blockIdx.y, n = blockIdx.z;
  const int s0 = blockIdx.x * 128 + wv * 32;  // this wave: q rows s0..s0+31
  const size_t hoff = ((size_t)(n * 16 + h)) * 2048 * 64;
  const bf16_t* Qb  = Q + hoff;
  const bf16_t* Kb  = K + hoff;
  const bf16_t* Vtb = Vt + hoff;

  // Q as B-operand: lane holds Q[row][c*32 + 8*lg + j]
  const bf16x8 qa0 = *(const bf16x8*)(Qb + (s0 + lq) * 64 + lg * 8);
  const bf16x8 qa1 = *(const bf16x8*)(Qb + (s0 + lq) * 64 + 32 + lg * 8);
  const bf16x8 qb0 = *(const bf16x8*)(Qb + (s0 + 16 + lq) * 64 + lg * 8);
  const bf16x8 qb1 = *(const bf16x8*)(Qb + (s0 + 16 + lq) * 64 + 32 + lg * 8);

  f32x4 oa[4] = {}, ob[4] = {};
  float ma = -1e30f, la = 0.f, mb = -1e30f, lb = 0.f;
  const int krperm = 8 * (lq >> 2) + (lq & 3);

  for (int kv = 0; kv < 2048; kv += 32) {
    const bf16_t* Kr = Kb + (size_t)(kv + krperm) * 64 + lg * 8;
    bf16x8 kf00 = *(const bf16x8*)(Kr);
    bf16x8 kf01 = *(const bf16x8*)(Kr + 32);
    bf16x8 kf10 = *(const bf16x8*)(Kr + 256);  // +4 key rows
    bf16x8 kf11 = *(const bf16x8*)(Kr + 288);

    // V^T fragment: lane holds Vt[16c+lq][kv + 8*lg + j] = V[kv+8lg+j][16c+lq]
    bf16x8 vf[4];
#pragma unroll
    for (int c = 0; c < 4; ++c)
      vf[c] = *(const bf16x8*)(Vtb + (size_t)(16 * c + lq) * 2048 + kv + lg * 8);

    f32x4 z = {};
    f32x4 sA0 = __builtin_amdgcn_mfma_f32_16x16x32_bf16(kf00, qa0, z, 0, 0, 0);
    sA0 = __builtin_amdgcn_mfma_f32_16x16x32_bf16(kf01, qa1, sA0, 0, 0, 0);
    f32x4 sA1 = __builtin_amdgcn_mfma_f32_16x16x32_bf16(kf10, qa0, z, 0, 0, 0);
    sA1 = __builtin_amdgcn_mfma_f32_16x16x32_bf16(kf11, qa1, sA1, 0, 0, 0);
    f32x4 sB0 = __builtin_amdgcn_mfma_f32_16x16x32_bf16(kf00, qb0, z, 0, 0, 0);
    sB0 = __builtin_amdgcn_mfma_f32_16x16x32_bf16(kf01, qb1, sB0, 0, 0, 0);
    f32x4 sB1 = __builtin_amdgcn_mfma_f32_16x16x32_bf16(kf10, qb0, z, 0, 0, 0);
    sB1 = __builtin_amdgcn_mfma_f32_16x16x32_bf16(kf11, qb1, sB1, 0, 0, 0);

    sm_pv(sA0, sA1, ma, la, vf, oa);
    sm_pv(sB0, sB1, mb, lb, vf, ob);
  }

  // o[c] lane layout: O[q=lq-row][c*16 + 4*lg + i]
  const float inva = 1.f / la;
  const float invb = 1.f / lb;
  bf16_t* AOa = AO + (((size_t)(n * 2048 + s0 + lq)) * 16 + h) * 64 + lg * 4;
  bf16_t* AOb = AO + (((size_t)(n * 2048 + s0 + 16 + lq)) * 16 + h) * 64 + lg * 4;
#pragma unroll
  for (int c = 0; c < 4; ++c) {
    bf16x4 w;
#pragma unroll
    for (int i = 0; i < 4; ++i) w[i] = (bf16_t)(oa[c][i] * inva);
    *(bf16x4*)(AOa + c * 16) = w;
#pragma unroll
    for (int i = 0; i < 4; ++i) w[i] = (bf16_t)(ob[c][i] * invb);
    *(bf16x4*)(AOb + c * 16) = w;
  }
}

// ---------------------------------------------------------------------------
extern "C" void kernel_launch(void* const* d_in, const int* in_sizes, int n_in,
                              void* d_out, int out_size, void* d_ws, size_t ws_size,
                              hipStream_t stream) {
  const float* values = (const float*)d_in[0];
  const float* keys   = (const float*)d_in[1];
  const float* query  = (const float*)d_in[2];
  const float* Wv     = (const float*)d_in[3];
  const float* Wk     = (const float*)d_in[4];
  const float* Wq     = (const float*)d_in[5];
  const float* Wo     = (const float*)d_in[6];
  float* out          = (float*)d_out;

  // workspace: 4 x 2MB bf16 weights (wv,wk,wq,wo), then q, k, vt, attn_out (16MB each)
  char* ws     = (char*)d_ws;
  bf16_t* wv_b = (bf16_t*)ws;
  bf16_t* wk_b = wv_b + (1u << 20);
  bf16_t* wq_b = wk_b + (1u << 20);
  bf16_t* wo_b = wq_b + (1u << 20);
  bf16_t* q_b  = wo_b + (1u << 20);
  bf16_t* k_b  = q_b + (8u << 20);
  bf16_t* vt_b = k_b + (8u << 20);
  bf16_t* ao_b = vt_b + (8u << 20);

  cvt_w_kernel<<<4096, 256, 0, stream>>>(Wv, Wk, Wq, Wo, wv_b);

  dim3 gg(64, 8);
  gemm_kernel<0, 0><<<gg, 256, 0, stream>>>(query, wq_b, q_b);
  gemm_kernel<0, 0><<<gg, 256, 0, stream>>>(keys, wk_b, k_b);
  gemm_kernel<0, 2><<<gg, 256, 0, stream>>>(values, wv_b, vt_b);

  attn_kernel<<<dim3(16, 16, 4), 256, 0, stream>>>(q_b, k_b, vt_b, ao_b);

  gemm_kernel<1, 1><<<gg, 256, 0, stream>>>(ao_b, wo_b, out);
}

// Round 5
// 521.722 us; speedup vs baseline: 1.2349x; 1.0105x over previous
//
#include <hip/hip_runtime.h>
#include <hip/hip_bf16.h>
#include <stdint.h>

typedef __bf16 bf16_t;
typedef __bf16 bf16x8 __attribute__((ext_vector_type(8)));
typedef __bf16 bf16x4 __attribute__((ext_vector_type(4)));
typedef float  f32x4  __attribute__((ext_vector_type(4)));

#define GL_LDS16(g, l)                                                         \
  __builtin_amdgcn_global_load_lds(                                            \
      (const __attribute__((address_space(1))) void*)(g),                      \
      (__attribute__((address_space(3))) void*)(l), 16, 0, 0)

// scores emerge from QK^T directly in exp2 domain: Q pre-scaled by this
#define SC2 0.04508422f  // (1/sqrt(1024)) * log2(e)

// ---------------------------------------------------------------------------
// fp32 -> bf16 conversion of the 4 weight matrices into contiguous ws:
// order wq, wk, wv, wo. grid = 4096 x 256, 4 elems/thread.
// ---------------------------------------------------------------------------
__global__ void cvt_w_kernel(const float* __restrict__ s0, const float* __restrict__ s1,
                             const float* __restrict__ s2, const float* __restrict__ s3,
                             bf16_t* __restrict__ dst) {
  const int b = blockIdx.x;
  const float* src = (b < 1024) ? s0 : (b < 2048) ? s1 : (b < 3072) ? s2 : s3;
  const int i = ((b & 1023) * 256 + threadIdx.x) * 4;
  f32x4 v = *(const f32x4*)(src + i);
  bf16x4 w;
  w[0] = (bf16_t)v[0]; w[1] = (bf16_t)v[1]; w[2] = (bf16_t)v[2]; w[3] = (bf16_t)v[3];
  *(bf16x4*)(dst + (size_t)(b >> 10) * (1u << 20) + i) = w;
}

// ---------------------------------------------------------------------------
// Fused q/k/v projection: z=0 -> q (scaled by SC2, [n][h][s][d])
//                         z=1 -> k ([n][h][s][d])
//                         z=2 -> v transposed ([n][h][d][s])
// A fp32 [8192][1024], W bf16 [1024][1024] (row = out). 128x128 tile, BK=64,
// 4 waves, mfma 16x16x32 bf16, linear LDS, global_load_lds for W.
// ---------------------------------------------------------------------------
__global__ __launch_bounds__(256) void proj_kernel(const float* __restrict__ Aq,
                                                   const float* __restrict__ Ak,
                                                   const float* __restrict__ Av,
                                                   const bf16_t* __restrict__ Wbase,
                                                   bf16_t* __restrict__ Oq,
                                                   bf16_t* __restrict__ Ok,
                                                   bf16_t* __restrict__ Ovt) {
  __shared__ char ldsA[128 * 64 * 2];
  __shared__ char ldsB[128 * 64 * 2];
  const int z  = blockIdx.z;
  const float* Af = (z == 0) ? Aq : (z == 1) ? Ak : Av;
  const bf16_t* Wptr = Wbase + ((size_t)z << 20);
  const int t  = threadIdx.x;
  const int l  = t & 63;
  const int wv = t >> 6;
  const int wr = wv >> 1, wc = wv & 1;
  const int lq = l & 15, lg = l >> 4;
  const int m0 = blockIdx.x * 128;
  const int n0 = blockIdx.y * 128;

  f32x4 acc[4][4] = {};

  for (int k0 = 0; k0 < 1024; k0 += 64) {
#pragma unroll
    for (int it = 0; it < 4; ++it) {
      const int dst = it * 4096 + t * 16;
      const int row = dst >> 7;
      const int col = (dst & 127) >> 1;
      GL_LDS16(Wptr + (size_t)(n0 + row) * 1024 + k0 + col, ldsB + dst);
    }
    {
      const int row   = t >> 1;
      const int cbase = (t & 1) * 32;
#pragma unroll
      for (int u = 0; u < 8; ++u) {
        const int colf = cbase + u * 4;
        f32x4 v = *(const f32x4*)(Af + (size_t)(m0 + row) * 1024 + k0 + colf);
        bf16x4 b;
        b[0] = (bf16_t)v[0]; b[1] = (bf16_t)v[1]; b[2] = (bf16_t)v[2]; b[3] = (bf16_t)v[3];
        *(bf16x4*)(ldsA + row * 128 + colf * 2) = b;
      }
    }
    __syncthreads();
#pragma unroll
    for (int kc = 0; kc < 2; ++kc) {
      bf16x8 af[4], bfr[4];
#pragma unroll
      for (int mm = 0; mm < 4; ++mm)
        af[mm] = *(const bf16x8*)(ldsA + (wr * 64 + mm * 16 + lq) * 128 + kc * 64 + lg * 16);
#pragma unroll
      for (int nn = 0; nn < 4; ++nn)
        bfr[nn] = *(const bf16x8*)(ldsB + (wc * 64 + nn * 16 + lq) * 128 + kc * 64 + lg * 16);
#pragma unroll
      for (int mm = 0; mm < 4; ++mm)
#pragma unroll
        for (int nn = 0; nn < 4; ++nn)
          acc[mm][nn] =
              __builtin_amdgcn_mfma_f32_16x16x32_bf16(af[mm], bfr[nn], acc[mm][nn], 0, 0, 0);
    }
    __syncthreads();
  }

  // D frag: row = 4*lg + i, col = lq
  if (z == 2) {
#pragma unroll
    for (int mm = 0; mm < 4; ++mm)
#pragma unroll
      for (int nn = 0; nn < 4; ++nn) {
        const int r  = m0 + wr * 64 + mm * 16 + lg * 4;
        const int c  = n0 + wc * 64 + nn * 16 + lq;
        const int nb = r >> 11, s = r & 2047;
        const int hh = c >> 6, d = c & 63;
        bf16x4 w;
#pragma unroll
        for (int i = 0; i < 4; ++i) w[i] = (bf16_t)acc[mm][nn][i];
        *(bf16x4*)(Ovt + (((size_t)nb * 16 + hh) * 64 + d) * 2048 + s) = w;
      }
  } else {
    bf16_t* O      = (z == 0) ? Oq : Ok;
    const float sc = (z == 0) ? SC2 : 1.0f;
#pragma unroll
    for (int mm = 0; mm < 4; ++mm)
#pragma unroll
      for (int nn = 0; nn < 4; ++nn) {
#pragma unroll
        for (int i = 0; i < 4; ++i) {
          const int r  = m0 + wr * 64 + mm * 16 + lg * 4 + i;
          const int c  = n0 + wc * 64 + nn * 16 + lq;
          const int nb = r >> 11, s = r & 2047;
          const int hh = c >> 6, d = c & 63;
          O[(((size_t)nb * 16 + hh) * 2048 + s) * 64 + d] = (bf16_t)(acc[mm][nn][i] * sc);
        }
      }
  }
}

// ---------------------------------------------------------------------------
// Output GEMM: out[8192][1024] fp32 = AO_bf16 @ Wo^T. Same 128x128 structure.
// ---------------------------------------------------------------------------
__global__ __launch_bounds__(256) void ogemm_kernel(const bf16_t* __restrict__ Ab,
                                                    const bf16_t* __restrict__ Wptr,
                                                    float* __restrict__ O) {
  __shared__ char ldsA[128 * 64 * 2];
  __shared__ char ldsB[128 * 64 * 2];
  const int t  = threadIdx.x;
  const int l  = t & 63;
  const int wv = t >> 6;
  const int wr = wv >> 1, wc = wv & 1;
  const int lq = l & 15, lg = l >> 4;
  const int m0 = blockIdx.x * 128;
  const int n0 = blockIdx.y * 128;

  f32x4 acc[4][4] = {};

  for (int k0 = 0; k0 < 1024; k0 += 64) {
#pragma unroll
    for (int it = 0; it < 4; ++it) {
      const int dst = it * 4096 + t * 16;
      const int row = dst >> 7;
      const int col = (dst & 127) >> 1;
      GL_LDS16(Wptr + (size_t)(n0 + row) * 1024 + k0 + col, ldsB + dst);
      GL_LDS16(Ab + (size_t)(m0 + row) * 1024 + k0 + col, ldsA + dst);
    }
    __syncthreads();
#pragma unroll
    for (int kc = 0; kc < 2; ++kc) {
      bf16x8 af[4], bfr[4];
#pragma unroll
      for (int mm = 0; mm < 4; ++mm)
        af[mm] = *(const bf16x8*)(ldsA + (wr * 64 + mm * 16 + lq) * 128 + kc * 64 + lg * 16);
#pragma unroll
      for (int nn = 0; nn < 4; ++nn)
        bfr[nn] = *(const bf16x8*)(ldsB + (wc * 64 + nn * 16 + lq) * 128 + kc * 64 + lg * 16);
#pragma unroll
      for (int mm = 0; mm < 4; ++mm)
#pragma unroll
        for (int nn = 0; nn < 4; ++nn)
          acc[mm][nn] =
              __builtin_amdgcn_mfma_f32_16x16x32_bf16(af[mm], bfr[nn], acc[mm][nn], 0, 0, 0);
    }
    __syncthreads();
  }
#pragma unroll
  for (int mm = 0; mm < 4; ++mm)
#pragma unroll
    for (int nn = 0; nn < 4; ++nn) {
      const int r = m0 + wr * 64 + mm * 16 + lg * 4;
      const int c = n0 + wc * 64 + nn * 16 + lq;
#pragma unroll
      for (int i = 0; i < 4; ++i) O[(size_t)(r + i) * 1024 + c] = acc[mm][nn][i];
    }
}

// ---------------------------------------------------------------------------
// Flash attention. q (pre-scaled by SC2), k: bf16 [n][h][s][64];
// v: bf16 transposed [n][h][d][s]; out bf16 [n][s][h][64].
// 1D grid, XCD-chunked swizzle: each XCD owns 8 complete heads -> K/V L2-hit.
// 4 waves/block, wave owns 32 q rows. No LDS. K prefetched one 32-key tile
// ahead (manual 2x unroll, named regs). Defer-max softmax in exp2 domain.
// ---------------------------------------------------------------------------
__device__ __forceinline__ void sm_pv(const f32x4& s0v, const f32x4& s1v, float& mrun,
                                      float& lsum, const bf16x8 vf[4], f32x4 o[4]) {
  float s[8];
#pragma unroll
  for (int i = 0; i < 4; ++i) { s[i] = s0v[i]; s[4 + i] = s1v[i]; }
  float tm = fmaxf(fmaxf(fmaxf(s[0], s[1]), fmaxf(s[2], s[3])),
                   fmaxf(fmaxf(s[4], s[5]), fmaxf(s[6], s[7])));
  tm = fmaxf(tm, __shfl_xor(tm, 16));
  tm = fmaxf(tm, __shfl_xor(tm, 32));
  if (__any(tm > mrun + 8.f)) {  // wave-uniform rescale (rare after first tile)
    const float mnew = fmaxf(mrun, tm);
    const float corr = exp2f(mrun - mnew);
    lsum *= corr;
#pragma unroll
    for (int c = 0; c < 4; ++c)
#pragma unroll
      for (int i = 0; i < 4; ++i) o[c][i] *= corr;
    mrun = mnew;
  }
  float p[8], ps = 0.f;
#pragma unroll
  for (int j = 0; j < 8; ++j) { p[j] = exp2f(s[j] - mrun); ps += p[j]; }
  ps += __shfl_xor(ps, 16);
  ps += __shfl_xor(ps, 32);
  lsum += ps;
  bf16x8 pf;
#pragma unroll
  for (int j = 0; j < 8; ++j) pf[j] = (bf16_t)p[j];
  __builtin_amdgcn_s_setprio(1);
#pragma unroll
  for (int c = 0; c < 4; ++c)
    o[c] = __builtin_amdgcn_mfma_f32_16x16x32_bf16(vf[c], pf, o[c], 0, 0, 0);
  __builtin_amdgcn_s_setprio(0);
}

__global__ __launch_bounds__(256, 4) void attn_kernel(const bf16_t* __restrict__ Q,
                                                      const bf16_t* __restrict__ K,
                                                      const bf16_t* __restrict__ Vt,
                                                      bf16_t* __restrict__ AO) {
  const int t  = threadIdx.x;
  const int l  = t & 63;
  const int wv = t >> 6;
  const int lq = l & 15, lg = l >> 4;
  // XCD-chunked swizzle: 1024 wgs, 8 XCDs, 128 consecutive flat ids per XCD
  const int bid  = blockIdx.x;
  const int flat = (bid & 7) * 128 + (bid >> 3);
  const int qb = flat & 15, h = (flat >> 4) & 15, n = flat >> 8;
  const int s0 = qb * 128 + wv * 32;
  const size_t hoff = ((size_t)(n * 16 + h)) * 2048 * 64;
  const bf16_t* Qb  = Q + hoff;
  const bf16_t* Kb  = K + hoff;
  const bf16_t* Vtb = Vt + hoff;

  // Q as B-operand: lane holds Q[row][c*32 + 8*lg + j]
  const bf16x8 qx0 = *(const bf16x8*)(Qb + (s0 + lq) * 64 + lg * 8);
  const bf16x8 qx1 = *(const bf16x8*)(Qb + (s0 + lq) * 64 + 32 + lg * 8);
  const bf16x8 qy0 = *(const bf16x8*)(Qb + (s0 + 16 + lq) * 64 + lg * 8);
  const bf16x8 qy1 = *(const bf16x8*)(Qb + (s0 + 16 + lq) * 64 + 32 + lg * 8);

  f32x4 ox[4] = {}, oy[4] = {};
  float mx = -1e30f, lx = 0.f, my = -1e30f, ly = 0.f;
  const int krperm  = 8 * (lq >> 2) + (lq & 3);
  const bf16_t* Kp  = Kb + (size_t)krperm * 64 + lg * 8;

  bf16x8 kA0, kA1, kA2, kA3, kB0, kB1, kB2, kB3;

#define LDK(kvo, a, b, c, d)                                   \
  {                                                            \
    const bf16_t* Kr = Kp + (size_t)(kvo) * 64;                \
    a = *(const bf16x8*)(Kr);                                  \
    b = *(const bf16x8*)(Kr + 32);                             \
    c = *(const bf16x8*)(Kr + 256);                            \
    d = *(const bf16x8*)(Kr + 288);                            \
  }
#define LDV(kvo, vf)                                                               \
  {                                                                                \
    _Pragma("unroll") for (int c = 0; c < 4; ++c) vf[c] =                          \
        *(const bf16x8*)(Vtb + (size_t)(16 * c + lq) * 2048 + (kvo) + lg * 8);     \
  }
#define HALF(k0, k1, k2, k3, vf)                                                   \
  {                                                                                \
    f32x4 zz = {};                                                                 \
    __builtin_amdgcn_s_setprio(1);                                                 \
    f32x4 sX0 = __builtin_amdgcn_mfma_f32_16x16x32_bf16(k0, qx0, zz, 0, 0, 0);     \
    sX0 = __builtin_amdgcn_mfma_f32_16x16x32_bf16(k1, qx1, sX0, 0, 0, 0);          \
    f32x4 sX1 = __builtin_amdgcn_mfma_f32_16x16x32_bf16(k2, qx0, zz, 0, 0, 0);     \
    sX1 = __builtin_amdgcn_mfma_f32_16x16x32_bf16(k3, qx1, sX1, 0, 0, 0);          \
    f32x4 sY0 = __builtin_amdgcn_mfma_f32_16x16x32_bf16(k0, qy0, zz, 0, 0, 0);     \
    sY0 = __builtin_amdgcn_mfma_f32_16x16x32_bf16(k1, qy1, sY0, 0, 0, 0);          \
    f32x4 sY1 = __builtin_amdgcn_mfma_f32_16x16x32_bf16(k2, qy0, zz, 0, 0, 0);     \
    sY1 = __builtin_amdgcn_mfma_f32_16x16x32_bf16(k3, qy1, sY1, 0, 0, 0);          \
    __builtin_amdgcn_s_setprio(0);                                                 \
    sm_pv(sX0, sX1, mx, lx, vf, ox);                                               \
    sm_pv(sY0, sY1, my, ly, vf, oy);                                               \
  }

  LDK(0, kA0, kA1, kA2, kA3);
  for (int kv = 0; kv < 2048; kv += 64) {
    bf16x8 vA[4];
    LDV(kv, vA);
    LDK(kv + 32, kB0, kB1, kB2, kB3);
    HALF(kA0, kA1, kA2, kA3, vA);
    bf16x8 vB[4];
    LDV(kv + 32, vB);
    LDK((kv + 64) & 2047, kA0, kA1, kA2, kA3);  // last iter: harmless wrap
    HALF(kB0, kB1, kB2, kB3, vB);
  }
#undef LDK
#undef LDV
#undef HALF

  const float invx = 1.f / lx;
  const float invy = 1.f / ly;
  bf16_t* AOx = AO + (((size_t)(n * 2048 + s0 + lq)) * 16 + h) * 64 + lg * 4;
  bf16_t* AOy = AO + (((size_t)(n * 2048 + s0 + 16 + lq)) * 16 + h) * 64 + lg * 4;
#pragma unroll
  for (int c = 0; c < 4; ++c) {
    bf16x4 w;
#pragma unroll
    for (int i = 0; i < 4; ++i) w[i] = (bf16_t)(ox[c][i] * invx);
    *(bf16x4*)(AOx + c * 16) = w;
#pragma unroll
    for (int i = 0; i < 4; ++i) w[i] = (bf16_t)(oy[c][i] * invy);
    *(bf16x4*)(AOy + c * 16) = w;
  }
}

// ---------------------------------------------------------------------------
extern "C" void kernel_launch(void* const* d_in, const int* in_sizes, int n_in,
                              void* d_out, int out_size, void* d_ws, size_t ws_size,
                              hipStream_t stream) {
  const float* values = (const float*)d_in[0];
  const float* keys   = (const float*)d_in[1];
  const float* query  = (const float*)d_in[2];
  const float* Wv     = (const float*)d_in[3];
  const float* Wk     = (const float*)d_in[4];
  const float* Wq     = (const float*)d_in[5];
  const float* Wo     = (const float*)d_in[6];
  float* out          = (float*)d_out;

  // ws: weights bf16 in order wq,wk,wv,wo (1M elems each), then q,k,vt,ao
  char* ws     = (char*)d_ws;
  bf16_t* w_b  = (bf16_t*)ws;
  bf16_t* wo_b = w_b + (3u << 20);
  bf16_t* q_b  = w_b + (4u << 20);
  bf16_t* k_b  = q_b + (8u << 20);
  bf16_t* vt_b = k_b + (8u << 20);
  bf16_t* ao_b = vt_b + (8u << 20);

  cvt_w_kernel<<<4096, 256, 0, stream>>>(Wq, Wk, Wv, Wo, w_b);

  proj_kernel<<<dim3(64, 8, 3), 256, 0, stream>>>(query, keys, values, w_b, q_b, k_b, vt_b);

  attn_kernel<<<1024, 256, 0, stream>>>(q_b, k_b, vt_b, ao_b);

  ogemm_kernel<<<dim3(64, 8), 256, 0, stream>>>(ao_b, wo_b, out);
}

// Round 7
// 376.143 us; speedup vs baseline: 1.7128x; 1.3870x over previous
//
#include <hip/hip_runtime.h>
#include <hip/hip_bf16.h>
#include <stdint.h>

typedef __bf16 bf16_t;
typedef __bf16 bf16x8 __attribute__((ext_vector_type(8)));
typedef __bf16 bf16x4 __attribute__((ext_vector_type(4)));
typedef float  f32x4  __attribute__((ext_vector_type(4)));

#define GL_LDS16(g, l)                                                         \
  __builtin_amdgcn_global_load_lds(                                            \
      (const __attribute__((address_space(1))) void*)(g),                      \
      (__attribute__((address_space(3))) void*)(l), 16, 0, 0)

#define MFMA16 __builtin_amdgcn_mfma_f32_16x16x32_bf16

// scores emerge from QK^T directly in exp2 domain: Q pre-scaled by this
#define SC2 0.04508422f  // (1/sqrt(1024)) * log2(e)

// ---------------------------------------------------------------------------
// fp32 -> bf16 conversion of the 4 weight matrices into contiguous ws:
// order wq, wk, wv, wo. grid = 4096 x 256, 4 elems/thread.
// ---------------------------------------------------------------------------
__global__ void cvt_w_kernel(const float* __restrict__ s0, const float* __restrict__ s1,
                             const float* __restrict__ s2, const float* __restrict__ s3,
                             bf16_t* __restrict__ dst) {
  const int b = blockIdx.x;
  const float* src = (b < 1024) ? s0 : (b < 2048) ? s1 : (b < 3072) ? s2 : s3;
  const int i = ((b & 1023) * 256 + threadIdx.x) * 4;
  f32x4 v = *(const f32x4*)(src + i);
  bf16x4 w;
  w[0] = (bf16_t)v[0]; w[1] = (bf16_t)v[1]; w[2] = (bf16_t)v[2]; w[3] = (bf16_t)v[3];
  *(bf16x4*)(dst + (size_t)(b >> 10) * (1u << 20) + i) = w;
}

// ---------------------------------------------------------------------------
// Fused q/k/v projection. z=0 -> q (scaled by SC2, [n][h][s][d])
//                         z=1 -> k ([n][h][s][d])
//                         z=2 -> v transposed ([n][h][d][s])
// XCD-chunked block swizzle: 512 blocks/plane, each XCD owns 8 full row-panels
// so the 8 col-blocks sharing an A-panel land on one XCD's L2.
// A staged fp32->bf16 with coalesced 256B global reads + lane-linear LDS
// writes (old pattern was a ~32-way LDS write bank conflict).
// ---------------------------------------------------------------------------
__global__ __launch_bounds__(256) void proj_kernel(const float* __restrict__ Aq,
                                                   const float* __restrict__ Ak,
                                                   const float* __restrict__ Av,
                                                   const bf16_t* __restrict__ Wbase,
                                                   bf16_t* __restrict__ Oq,
                                                   bf16_t* __restrict__ Ok,
                                                   bf16_t* __restrict__ Ovt) {
  __shared__ char ldsA[128 * 64 * 2];
  __shared__ char ldsB[128 * 64 * 2];
  const int z  = blockIdx.z;
  const float* Af = (z == 0) ? Aq : (z == 1) ? Ak : Av;
  const bf16_t* Wptr = Wbase + ((size_t)z << 20);
  const int t  = threadIdx.x;
  const int l  = t & 63;
  const int wv = t >> 6;
  const int wr = wv >> 1, wc = wv & 1;
  const int lq = l & 15, lg = l >> 4;
  // XCD-chunked swizzle over the 64x8 tile grid
  const int bid = blockIdx.x + (blockIdx.y << 6);  // 0..511
  const int pm  = (bid & 7) * 64 + (bid >> 3);     // panel-major id
  const int m0  = (pm >> 3) * 128;
  const int n0  = (pm & 7) * 128;

  const int ar = t >> 4;         // 0..15: row within a 16-row group
  const int ac = (t & 15) * 4;   // float column

  f32x4 acc[4][4] = {};

  for (int k0 = 0; k0 < 1024; k0 += 64) {
#pragma unroll
    for (int it = 0; it < 4; ++it) {
      const int dst = it * 4096 + t * 16;
      const int row = dst >> 7;
      const int col = (dst & 127) >> 1;
      GL_LDS16(Wptr + (size_t)(n0 + row) * 1024 + k0 + col, ldsB + dst);
    }
#pragma unroll
    for (int u = 0; u < 8; ++u) {
      const int row = u * 16 + ar;
      f32x4 v = *(const f32x4*)(Af + (size_t)(m0 + row) * 1024 + k0 + ac);
      bf16x4 b;
      b[0] = (bf16_t)v[0]; b[1] = (bf16_t)v[1]; b[2] = (bf16_t)v[2]; b[3] = (bf16_t)v[3];
      *(bf16x4*)(ldsA + row * 128 + ac * 2) = b;
    }
    __syncthreads();
#pragma unroll
    for (int kc = 0; kc < 2; ++kc) {
      bf16x8 af[4], bfr[4];
#pragma unroll
      for (int mm = 0; mm < 4; ++mm)
        af[mm] = *(const bf16x8*)(ldsA + (wr * 64 + mm * 16 + lq) * 128 + kc * 64 + lg * 16);
#pragma unroll
      for (int nn = 0; nn < 4; ++nn)
        bfr[nn] = *(const bf16x8*)(ldsB + (wc * 64 + nn * 16 + lq) * 128 + kc * 64 + lg * 16);
#pragma unroll
      for (int mm = 0; mm < 4; ++mm)
#pragma unroll
        for (int nn = 0; nn < 4; ++nn)
          acc[mm][nn] = MFMA16(af[mm], bfr[nn], acc[mm][nn], 0, 0, 0);
    }
    __syncthreads();
  }

  // D frag: row = 4*lg + i, col = lq
  if (z == 2) {
#pragma unroll
    for (int mm = 0; mm < 4; ++mm)
#pragma unroll
      for (int nn = 0; nn < 4; ++nn) {
        const int r  = m0 + wr * 64 + mm * 16 + lg * 4;
        const int c  = n0 + wc * 64 + nn * 16 + lq;
        const int nb = r >> 11, s = r & 2047;
        const int hh = c >> 6, d = c & 63;
        bf16x4 w;
#pragma unroll
        for (int i = 0; i < 4; ++i) w[i] = (bf16_t)acc[mm][nn][i];
        *(bf16x4*)(Ovt + (((size_t)nb * 16 + hh) * 64 + d) * 2048 + s) = w;
      }
  } else {
    bf16_t* O      = (z == 0) ? Oq : Ok;
    const float sc = (z == 0) ? SC2 : 1.0f;
#pragma unroll
    for (int mm = 0; mm < 4; ++mm)
#pragma unroll
      for (int nn = 0; nn < 4; ++nn) {
#pragma unroll
        for (int i = 0; i < 4; ++i) {
          const int r  = m0 + wr * 64 + mm * 16 + lg * 4 + i;
          const int c  = n0 + wc * 64 + nn * 16 + lq;
          const int nb = r >> 11, s = r & 2047;
          const int hh = c >> 6, d = c & 63;
          O[(((size_t)nb * 16 + hh) * 2048 + s) * 64 + d] = (bf16_t)(acc[mm][nn][i] * sc);
        }
      }
  }
}

// ---------------------------------------------------------------------------
// Output GEMM: out[8192][1024] fp32 = AO_bf16 @ Wo^T. Same structure + swizzle.
// ---------------------------------------------------------------------------
__global__ __launch_bounds__(256) void ogemm_kernel(const bf16_t* __restrict__ Ab,
                                                    const bf16_t* __restrict__ Wptr,
                                                    float* __restrict__ O) {
  __shared__ char ldsA[128 * 64 * 2];
  __shared__ char ldsB[128 * 64 * 2];
  const int t  = threadIdx.x;
  const int l  = t & 63;
  const int wv = t >> 6;
  const int wr = wv >> 1, wc = wv & 1;
  const int lq = l & 15, lg = l >> 4;
  const int bid = blockIdx.x + (blockIdx.y << 6);
  const int pm  = (bid & 7) * 64 + (bid >> 3);
  const int m0  = (pm >> 3) * 128;
  const int n0  = (pm & 7) * 128;

  f32x4 acc[4][4] = {};

  for (int k0 = 0; k0 < 1024; k0 += 64) {
#pragma unroll
    for (int it = 0; it < 4; ++it) {
      const int dst = it * 4096 + t * 16;
      const int row = dst >> 7;
      const int col = (dst & 127) >> 1;
      GL_LDS16(Wptr + (size_t)(n0 + row) * 1024 + k0 + col, ldsB + dst);
      GL_LDS16(Ab + (size_t)(m0 + row) * 1024 + k0 + col, ldsA + dst);
    }
    __syncthreads();
#pragma unroll
    for (int kc = 0; kc < 2; ++kc) {
      bf16x8 af[4], bfr[4];
#pragma unroll
      for (int mm = 0; mm < 4; ++mm)
        af[mm] = *(const bf16x8*)(ldsA + (wr * 64 + mm * 16 + lq) * 128 + kc * 64 + lg * 16);
#pragma unroll
      for (int nn = 0; nn < 4; ++nn)
        bfr[nn] = *(const bf16x8*)(ldsB + (wc * 64 + nn * 16 + lq) * 128 + kc * 64 + lg * 16);
#pragma unroll
      for (int mm = 0; mm < 4; ++mm)
#pragma unroll
        for (int nn = 0; nn < 4; ++nn)
          acc[mm][nn] = MFMA16(af[mm], bfr[nn], acc[mm][nn], 0, 0, 0);
    }
    __syncthreads();
  }
#pragma unroll
  for (int mm = 0; mm < 4; ++mm)
#pragma unroll
    for (int nn = 0; nn < 4; ++nn) {
      const int r = m0 + wr * 64 + mm * 16 + lg * 4;
      const int c = n0 + wc * 64 + nn * 16 + lq;
#pragma unroll
      for (int i = 0; i < 4; ++i) O[(size_t)(r + i) * 1024 + c] = acc[mm][nn][i];
    }
}

// ---------------------------------------------------------------------------
// Flash attention. q (pre-scaled by SC2), k: bf16 [n][h][s][64];
// v: bf16 transposed [n][h][d][s]; out bf16 [n][s][h][64].
// XCD-chunked grid (each XCD owns 8 complete heads -> K/V L2-resident).
// Block-cooperative double-buffered LDS staging of 64-key K/V tiles.
// LDS layout is fragment-order lane-linear (permutation folded into the
// per-lane GLOBAL source address of global_load_lds => stride-1 conflict-free
// ds_read_b128 on consumption). Counted vmcnt(4) + raw s_barrier 2-phase.
// Softmax: lane-local lsum (cross-lane reduce once at epilogue) and the
// max-reduce shuffles run only when __any(local max grew past m+8) -- the
// common-case step has ZERO DS ops in the softmax chain.
// ---------------------------------------------------------------------------
__device__ __forceinline__ void sm_pv(const f32x4& s0v, const f32x4& s1v, float& mrun,
                                      float& lsum, const bf16x8 vf[4], f32x4 o[4]) {
  float s[8];
#pragma unroll
  for (int i = 0; i < 4; ++i) { s[i] = s0v[i]; s[4 + i] = s1v[i]; }
  float tm = fmaxf(fmaxf(fmaxf(s[0], s[1]), fmaxf(s[2], s[3])),
                   fmaxf(fmaxf(s[4], s[5]), fmaxf(s[6], s[7])));
  if (__any(tm > mrun + 8.f)) {  // rare after warm-up: full reduce + rescale
    tm = fmaxf(tm, __shfl_xor(tm, 16));
    tm = fmaxf(tm, __shfl_xor(tm, 32));
    const float mnew = fmaxf(mrun, tm);
    const float corr = exp2f(mrun - mnew);
    lsum *= corr;
#pragma unroll
    for (int c = 0; c < 4; ++c)
#pragma unroll
      for (int i = 0; i < 4; ++i) o[c][i] *= corr;
    mrun = mnew;
  }
  float p[8], ps = 0.f;
#pragma unroll
  for (int j = 0; j < 8; ++j) { p[j] = exp2f(s[j] - mrun); ps += p[j]; }
  lsum += ps;  // lane-local partial; reduced across lanes at epilogue
  bf16x8 pf;
#pragma unroll
  for (int j = 0; j < 8; ++j) pf[j] = (bf16_t)p[j];
  __builtin_amdgcn_s_setprio(1);
#pragma unroll
  for (int c = 0; c < 4; ++c) o[c] = MFMA16(vf[c], pf, o[c], 0, 0, 0);
  __builtin_amdgcn_s_setprio(0);
}

__global__ __launch_bounds__(256, 4) void attn_kernel(const bf16_t* __restrict__ Q,
                                                      const bf16_t* __restrict__ K,
                                                      const bf16_t* __restrict__ Vt,
                                                      bf16_t* __restrict__ AO) {
  // double-buffered: [2] x { K 8KB (8 groups x 1KB) | V 8KB (8 groups x 1KB) }
  __shared__ char ldsc[32768];
  const int t  = threadIdx.x;
  const int l  = t & 63;
  const int wv = t >> 6;
  const int lq = l & 15, lg = l >> 4;
  const int bid  = blockIdx.x;
  const int flat = (bid & 7) * 128 + (bid >> 3);
  const int qb = flat & 15, h = (flat >> 4) & 15, n = flat >> 8;
  const int s0 = qb * 128 + wv * 32;
  const size_t hoff = ((size_t)(n * 16 + h)) * 2048 * 64;
  const bf16_t* Qb  = Q + hoff;
  const bf16_t* Kb  = K + hoff;
  const bf16_t* Vtb = Vt + hoff;

  // Q as B-operand: lane holds Q[row][c*32 + 8*lg + j]
  const bf16x8 qx0 = *(const bf16x8*)(Qb + (s0 + lq) * 64 + lg * 8);
  const bf16x8 qx1 = *(const bf16x8*)(Qb + (s0 + lq) * 64 + 32 + lg * 8);
  const bf16x8 qy0 = *(const bf16x8*)(Qb + (s0 + 16 + lq) * 64 + lg * 8);
  const bf16x8 qy1 = *(const bf16x8*)(Qb + (s0 + 16 + lq) * 64 + 32 + lg * 8);

  f32x4 ox[4] = {}, oy[4] = {};
  float mx = -1e30f, lx = 0.f, my = -1e30f, ly = 0.f;

  // staging source coordinates: thread t fills fragment-order slot t (+256)
  const int g1      = t >> 6;                          // K/V group 0..3
  const int lqt     = t & 15;
  const int lgt     = (t >> 4) & 3;
  const int kperm_t = 8 * (lqt >> 2) + (lqt & 3);      // fragment row perm
  const int krow0   = (g1 >> 1) * 4 + kperm_t;         // key row in tile
  const int kcol0   = (g1 & 1) * 32 + lgt * 8;         // d column
  const int vrow0   = 16 * g1 + lqt;                   // d row of Vt
  const int vcol0   = lgt * 8;                         // key col in tile

#define STAGE(bofs, kt)                                                           \
  {                                                                               \
    const int kv0_ = (kt) * 64;                                                   \
    GL_LDS16(Kb + (size_t)(kv0_ + krow0) * 64 + kcol0, ldsc + (bofs) + t * 16);   \
    GL_LDS16(Kb + (size_t)(kv0_ + krow0 + 32) * 64 + kcol0,                       \
             ldsc + (bofs) + 4096 + t * 16);                                      \
    GL_LDS16(Vtb + (size_t)vrow0 * 2048 + kv0_ + vcol0,                           \
             ldsc + (bofs) + 8192 + t * 16);                                      \
    GL_LDS16(Vtb + (size_t)vrow0 * 2048 + kv0_ + vcol0 + 32,                      \
             ldsc + (bofs) + 12288 + t * 16);                                     \
  }
#define WAITV4 asm volatile("s_waitcnt vmcnt(4)" ::: "memory")
#define WAITV0 asm volatile("s_waitcnt vmcnt(0)" ::: "memory")
#define BARRIER                                                                   \
  __builtin_amdgcn_s_barrier();                                                   \
  __builtin_amdgcn_sched_barrier(0)
#define STEP(PB)                                                                  \
  {                                                                               \
    const char* kp_ = (const char*)ldsc + (PB) + l * 16;                          \
    const bf16x8 kf0 = *(const bf16x8*)(kp_);                                     \
    const bf16x8 kf1 = *(const bf16x8*)(kp_ + 1024);                              \
    const bf16x8 kf2 = *(const bf16x8*)(kp_ + 2048);                              \
    const bf16x8 kf3 = *(const bf16x8*)(kp_ + 3072);                              \
    bf16x8 vfr[4];                                                                \
    vfr[0] = *(const bf16x8*)(kp_ + 8192);                                        \
    vfr[1] = *(const bf16x8*)(kp_ + 9216);                                        \
    vfr[2] = *(const bf16x8*)(kp_ + 10240);                                       \
    vfr[3] = *(const bf16x8*)(kp_ + 11264);                                       \
    f32x4 zz = {};                                                                \
    __builtin_amdgcn_s_setprio(1);                                                \
    f32x4 sX0 = MFMA16(kf0, qx0, zz, 0, 0, 0);                                    \
    sX0 = MFMA16(kf1, qx1, sX0, 0, 0, 0);                                         \
    f32x4 sX1 = MFMA16(kf2, qx0, zz, 0, 0, 0);                                    \
    sX1 = MFMA16(kf3, qx1, sX1, 0, 0, 0);                                         \
    f32x4 sY0 = MFMA16(kf0, qy0, zz, 0, 0, 0);                                    \
    sY0 = MFMA16(kf1, qy1, sY0, 0, 0, 0);                                         \
    f32x4 sY1 = MFMA16(kf2, qy0, zz, 0, 0, 0);                                    \
    sY1 = MFMA16(kf3, qy1, sY1, 0, 0, 0);                                         \
    __builtin_amdgcn_s_setprio(0);                                                \
    sm_pv(sX0, sX1, mx, lx, vfr, ox);                                             \
    sm_pv(sY0, sY1, my, ly, vfr, oy);                                             \
  }

  STAGE(0, 0);
  for (int kt = 0; kt < 32; kt += 2) {
    // tile kt from buf0; prefetch kt+1 into buf1 (kt+1 <= 31 always)
    STAGE(16384, kt + 1);
    WAITV4;
    BARRIER;
    STEP(0);
    STEP(4096);
    BARRIER;
    // tile kt+1 from buf1; prefetch kt+2 into buf0
    if (kt + 2 < 32) {
      STAGE(0, kt + 2);
      WAITV4;
    } else {
      WAITV0;
    }
    BARRIER;
    STEP(16384);
    STEP(16384 + 4096);
    BARRIER;
  }
#undef STAGE
#undef WAITV4
#undef WAITV0
#undef BARRIER
#undef STEP

  // epilogue: cross-lane lsum reduce (once), normalize, store
  lx += __shfl_xor(lx, 16); lx += __shfl_xor(lx, 32);
  ly += __shfl_xor(ly, 16); ly += __shfl_xor(ly, 32);
  const float invx = 1.f / lx;
  const float invy = 1.f / ly;
  bf16_t* AOx = AO + (((size_t)(n * 2048 + s0 + lq)) * 16 + h) * 64 + lg * 4;
  bf16_t* AOy = AO + (((size_t)(n * 2048 + s0 + 16 + lq)) * 16 + h) * 64 + lg * 4;
#pragma unroll
  for (int c = 0; c < 4; ++c) {
    bf16x4 w;
#pragma unroll
    for (int i = 0; i < 4; ++i) w[i] = (bf16_t)(ox[c][i] * invx);
    *(bf16x4*)(AOx + c * 16) = w;
#pragma unroll
    for (int i = 0; i < 4; ++i) w[i] = (bf16_t)(oy[c][i] * invy);
    *(bf16x4*)(AOy + c * 16) = w;
  }
}

// ---------------------------------------------------------------------------
extern "C" void kernel_launch(void* const* d_in, const int* in_sizes, int n_in,
                              void* d_out, int out_size, void* d_ws, size_t ws_size,
                              hipStream_t stream) {
  const float* values = (const float*)d_in[0];
  const float* keys   = (const float*)d_in[1];
  const float* query  = (const float*)d_in[2];
  const float* Wv     = (const float*)d_in[3];
  const float* Wk     = (const float*)d_in[4];
  const float* Wq     = (const float*)d_in[5];
  const float* Wo     = (const float*)d_in[6];
  float* out          = (float*)d_out;

  // ws: weights bf16 in order wq,wk,wv,wo (1M elems each), then q,k,vt,ao
  char* ws     = (char*)d_ws;
  bf16_t* w_b  = (bf16_t*)ws;
  bf16_t* wo_b = w_b + (3u << 20);
  bf16_t* q_b  = w_b + (4u << 20);
  bf16_t* k_b  = q_b + (8u << 20);
  bf16_t* vt_b = k_b + (8u << 20);
  bf16_t* ao_b = vt_b + (8u << 20);

  cvt_w_kernel<<<4096, 256, 0, stream>>>(Wq, Wk, Wv, Wo, w_b);

  proj_kernel<<<dim3(64, 8, 3), 256, 0, stream>>>(query, keys, values, w_b, q_b, k_b, vt_b);

  attn_kernel<<<1024, 256, 0, stream>>>(q_b, k_b, vt_b, ao_b);

  ogemm_kernel<<<dim3(64, 8), 256, 0, stream>>>(ao_b, wo_b, out);
}